// Round 5
// baseline (390.841 us; speedup 1.0000x reference)
//
#include <hip/hip_runtime.h>
#include <hip/hip_bf16.h>

#define B_ 8
#define S_ 2048
#define H_ 256
#define BS_ (B_*S_)

typedef __attribute__((ext_vector_type(8))) short bf16x8;
typedef __attribute__((ext_vector_type(4))) short bf16x4;
typedef __attribute__((ext_vector_type(4))) float f32x4;

static __device__ inline short f2bf(float f) {
  union { float f; unsigned int u; } a; a.f = f;
  unsigned int u = a.u;
  unsigned int r = (u + 0x7fffu + ((u >> 16) & 1u)) >> 16;
  return (short)r;
}

static __device__ inline float bf2f(short s) {
  union { float f; unsigned int u; } a;
  a.u = ((unsigned int)(unsigned short)s) << 16;
  return a.f;
}

static __device__ inline f32x4 mfma16(bf16x8 a, bf16x8 b, f32x4 c) {
  return __builtin_amdgcn_mfma_f32_16x16x32_bf16(a, b, c, 0, 0, 0);
}

// ---------------------------------------------------------------------------
// Kernel 0: fp32 -> bf16 conversion of x, Wq, Wk, Wv into workspace.
// ---------------------------------------------------------------------------
#define NX4 (BS_ * H_ / 4)
#define NW4 (H_ * H_ / 4)
#define NTOT4 (NX4 + 3 * NW4)

__global__ __launch_bounds__(256) void cvt_bf16(
    const float* __restrict__ x,
    const float* __restrict__ Wq, const float* __restrict__ Wk,
    const float* __restrict__ Wv,
    short* __restrict__ xb, short* __restrict__ wqb,
    short* __restrict__ wkb, short* __restrict__ wvb)
{
  int stride = gridDim.x * blockDim.x;
  for (int i = blockIdx.x * blockDim.x + threadIdx.x; i < NTOT4; i += stride) {
    const float* src; short* dst; int off;
    if (i < NX4) { src = x; dst = xb; off = i; }
    else {
      int j = i - NX4;
      int w = j >> 14;
      off = j & (NW4 - 1);
      src = (w == 0) ? Wq : (w == 1) ? Wk : Wv;
      dst = (w == 0) ? wqb : (w == 1) ? wkb : wvb;
    }
    float4 v = *(const float4*)(src + off * 4);
    bf16x4 p;
    p[0] = f2bf(v.x); p[1] = f2bf(v.y); p[2] = f2bf(v.z); p[3] = f2bf(v.w);
    *(bf16x4*)(dst + off * 4) = p;
  }
}

// ---------------------------------------------------------------------------
// Kernel 1: Q/K row-major + V transposed [b][h][k]. grid (BS/64, 3), block 256.
// ---------------------------------------------------------------------------
__global__ __launch_bounds__(256) void qkv_proj(
    const short* __restrict__ x,
    const short* __restrict__ Wq, const float* __restrict__ bq,
    const short* __restrict__ Wk, const float* __restrict__ bk,
    const short* __restrict__ Wv, const float* __restrict__ bv,
    short* __restrict__ Qo, short* __restrict__ Ko, short* __restrict__ VTo)
{
  const int tid  = threadIdx.x;
  const int wave = tid >> 6;
  const int lane = tid & 63;
  const int quad = lane >> 4;
  const int l16  = lane & 15;
  const int y    = blockIdx.y;

  const short* W    = (y == 0) ? Wq : (y == 1) ? Wk : Wv;
  const float* bias = (y == 0) ? bq : (y == 1) ? bk : bv;
  const int s0 = blockIdx.x * 64 + wave * 16;

  f32x4 zero = {0.f, 0.f, 0.f, 0.f};
  f32x4 acc[16];
#pragma unroll
  for (int i = 0; i < 16; i++) acc[i] = zero;

  const short* xrow = x + (s0 + l16) * H_ + quad * 8;
#pragma unroll
  for (int ks = 0; ks < 8; ks++) {
    bf16x8 a = *(const bf16x8*)(xrow + ks * 32);
#pragma unroll
    for (int nf = 0; nf < 16; nf++) {
      bf16x8 bb = *(const bf16x8*)(W + (nf * 16 + l16) * H_ + ks * 32 + quad * 8);
      acc[nf] = mfma16(a, bb, acc[nf]);
    }
  }

  if (y < 2) {
    short* dst = (y == 0) ? Qo : Ko;
#pragma unroll
    for (int nf = 0; nf < 16; nf++) {
      int col = nf * 16 + l16;
      float bvl = bias[col];
#pragma unroll
      for (int r = 0; r < 4; r++) {
        int row = s0 + quad * 4 + r;
        dst[row * H_ + col] = f2bf(acc[nf][r] + bvl);
      }
    }
  } else {
    int row0  = s0 + quad * 4;
    int b_idx = row0 >> 11;
    int k0    = row0 & (S_ - 1);
#pragma unroll
    for (int nf = 0; nf < 16; nf++) {
      int col = nf * 16 + l16;
      float bvl = bias[col];
      bf16x4 pk;
#pragma unroll
      for (int r = 0; r < 4; r++) pk[r] = f2bf(acc[nf][r] + bvl);
      *(bf16x4*)(VTo + (size_t)b_idx * H_ * S_ + (size_t)col * S_ + k0) = pk;
    }
  }
}

// ---------------------------------------------------------------------------
// Kernel 2a: zero den (BS_ floats) and out (BS_*H_ floats, 0xAA-poisoned).
// ---------------------------------------------------------------------------
__global__ __launch_bounds__(256) void zero_den(float* __restrict__ den)
{
  int i = blockIdx.x * 256 + threadIdx.x;
  if (i < BS_) den[i] = 0.f;
}

__global__ __launch_bounds__(256) void zero_out(float* __restrict__ out)
{
  int i = blockIdx.x * 256 + threadIdx.x;   // one float4 per thread
  float4 z = {0.f, 0.f, 0.f, 0.f};
  *(float4*)(out + (size_t)i * 4) = z;
}

// ---------------------------------------------------------------------------
// Kernel 2b: P = exp(QK^T/256) stored in A-FRAGMENT-LINEARIZED layout:
//   Pf[b][q/16][k/32][lane][8]  (tile = 512 bf16 = 1 KiB, lane=quad_A*16+l16_A)
//   where A-frag: lane(l16_A=q%16, quad_A), elem j -> k%32 = quad_A*8+j.
// Computed as S^T = K.Q^T; C-frag regs (4 contiguous k for fixed q) map to
// quad_A = 2*kf+(quad>>1), j0 = (quad&1)*4, an aligned 8-byte chunk.
// den[b][k] += row-sums. grid 2048 = b(8) x kt(16) x qt(16), block 256.
// ---------------------------------------------------------------------------
__global__ __launch_bounds__(256) void scores(
    const short* __restrict__ Q, const short* __restrict__ K,
    short* __restrict__ Pf, float* __restrict__ den)
{
  const int tid  = threadIdx.x;
  const int wave = tid >> 6;
  const int lane = tid & 63;
  const int quad = lane >> 4;
  const int l16  = lane & 15;
  const int qt = blockIdx.x & 15;
  const int kt = (blockIdx.x >> 4) & 15;
  const int b  = blockIdx.x >> 8;

  const short* Qb = Q + b * S_ * H_;
  const short* Kb = K + b * S_ * H_;

  const int krow0 = kt * 128 + wave * 32;
  const int qcol0 = qt * 128;
  const int kw    = krow0 >> 5;            // k-window (32 wide)

  f32x4 zero = {0.f, 0.f, 0.f, 0.f};
  f32x4 acc[2][8];
#pragma unroll
  for (int i = 0; i < 2; i++)
#pragma unroll
    for (int j = 0; j < 8; j++) acc[i][j] = zero;

#pragma unroll
  for (int kk = 0; kk < 8; kk++) {
    bf16x8 a0 = *(const bf16x8*)(Kb + (krow0 + l16) * H_ + kk * 32 + quad * 8);
    bf16x8 a1 = *(const bf16x8*)(Kb + (krow0 + 16 + l16) * H_ + kk * 32 + quad * 8);
#pragma unroll
    for (int qf = 0; qf < 8; qf++) {
      bf16x8 bq = *(const bf16x8*)(Qb + (qcol0 + qf * 16 + l16) * H_ + kk * 32 + quad * 8);
      acc[0][qf] = mfma16(a0, bq, acc[0][qf]);
      acc[1][qf] = mfma16(a1, bq, acc[1][qf]);
    }
  }

  const int quadA = quad >> 1;             // + 2*kf below
  const int j0    = (quad & 1) * 4;
  float rs[2][4] = {{0.f,0.f,0.f,0.f},{0.f,0.f,0.f,0.f}};
#pragma unroll
  for (int kf = 0; kf < 2; kf++) {
#pragma unroll
    for (int qf = 0; qf < 8; qf++) {
      bf16x4 pk;
#pragma unroll
      for (int r = 0; r < 4; r++) {
        float e = __expf(acc[kf][qf][r] * (1.0f / H_));
        rs[kf][r] += e;
        pk[r] = f2bf(e);
      }
      // tile index: (b*128 + q/16)*64 + kw ; elem offset in tile:
      // ((2*kf+quadA)*16 + l16)*8 + j0
      size_t tile = ((size_t)(b * 128 + qt * 8 + qf) << 6) + kw;
      *(bf16x4*)(Pf + (tile << 9) + ((2 * kf + quadA) * 16 + l16) * 8 + j0) = pk;
    }
  }

#pragma unroll
  for (int kf = 0; kf < 2; kf++) {
#pragma unroll
    for (int r = 0; r < 4; r++) {
      float v = rs[kf][r];
      v += __shfl_xor(v, 1, 64);
      v += __shfl_xor(v, 2, 64);
      v += __shfl_xor(v, 4, 64);
      v += __shfl_xor(v, 8, 64);
      if (l16 == 0)
        atomicAdd(&den[b * S_ + krow0 + kf * 16 + quad * 4 + r], v);
    }
  }
}

// ---------------------------------------------------------------------------
// Kernel 2c: rcp = 1/den.
// ---------------------------------------------------------------------------
__global__ __launch_bounds__(256) void den_rcp(
    const float* __restrict__ den, float* __restrict__ rcp)
{
  int i = blockIdx.x * 256 + threadIdx.x;
  if (i < BS_) rcp[i] = 1.0f / den[i];
}

// ---------------------------------------------------------------------------
// Kernel 2d: VT[b][h][k] *= rcp[b][k]  (fold softmax denom into V).
// ---------------------------------------------------------------------------
__global__ __launch_bounds__(256) void vscale(
    short* __restrict__ VT, const float* __restrict__ rcp)
{
  int i = blockIdx.x * 256 + threadIdx.x;     // bf16x4 group, k fastest
  int b  = i >> 17;
  int k0 = (i & 511) << 2;
  float4 rf = *(const float4*)(rcp + b * S_ + k0);
  bf16x4 v = *(bf16x4*)(VT + (size_t)i * 4);
  bf16x4 o;
  o[0] = f2bf(bf2f(v[0]) * rf.x);
  o[1] = f2bf(bf2f(v[1]) * rf.y);
  o[2] = f2bf(bf2f(v[2]) * rf.z);
  o[3] = f2bf(bf2f(v[3]) * rf.w);
  *(bf16x4*)(VT + (size_t)i * 4) = o;
}

// ---------------------------------------------------------------------------
// Kernel 3: out += P_slice . Vs_slice  (k-split x4, fp32 atomic accumulate).
// grid 2048 = b(8) x qt(32) x hs(2) x ks(4), block 256; wave: 16q x 128h x 512k.
// A loads are fully contiguous 1 KiB/wave thanks to Pf layout.
// ---------------------------------------------------------------------------
__global__ __launch_bounds__(256) void pv(
    const short* __restrict__ Pf, const short* __restrict__ VTs,
    float* __restrict__ out)
{
  const int tid  = threadIdx.x;
  const int wave = tid >> 6;
  const int lane = tid & 63;
  const int quad = lane >> 4;
  const int l16  = lane & 15;
  const int b  = blockIdx.x >> 8;
  const int rem = blockIdx.x & 255;
  const int qt = rem >> 3;
  const int hs = (rem >> 2) & 1;
  const int ks = rem & 3;

  const short* Vb = VTs + (size_t)b * H_ * S_ + (size_t)(hs * 128) * S_ + ks * 512;
  const int qt16 = qt * 4 + wave;          // q-tile (16 q) index

  // A-frag base: tile (b*128 + qt16)*64 + ks*16, each tile 512 elems
  const short* abase = Pf + (((size_t)(b * 128 + qt16) << 6) + (ks << 4) << 9) + lane * 8;

  f32x4 zero = {0.f, 0.f, 0.f, 0.f};
  f32x4 acc[8];
#pragma unroll
  for (int i = 0; i < 8; i++) acc[i] = zero;

#pragma unroll 4
  for (int kk = 0; kk < 16; kk++) {
    bf16x8 a = *(const bf16x8*)(abase + kk * 512);
#pragma unroll
    for (int n = 0; n < 8; n++) {
      bf16x8 vb = *(const bf16x8*)(Vb + (size_t)(n * 16 + l16) * S_ + kk * 32 + quad * 8);
      acc[n] = mfma16(a, vb, acc[n]);
    }
  }

  const int q0 = qt16 * 16;
#pragma unroll
  for (int n = 0; n < 8; n++) {
    int col = hs * 128 + n * 16 + l16;
#pragma unroll
    for (int r = 0; r < 4; r++) {
      int q = q0 + quad * 4 + r;
      atomicAdd(&out[((size_t)b * S_ + q) * H_ + col], acc[n][r]);
    }
  }
}

extern "C" void kernel_launch(void* const* d_in, const int* in_sizes, int n_in,
                              void* d_out, int out_size, void* d_ws, size_t ws_size,
                              hipStream_t stream) {
  const float* x  = (const float*)d_in[0];
  const float* Wq = (const float*)d_in[1];
  const float* bq = (const float*)d_in[2];
  const float* Wk = (const float*)d_in[3];
  const float* bk = (const float*)d_in[4];
  const float* Wv = (const float*)d_in[5];
  const float* bv = (const float*)d_in[6];

  short* xb  = (short*)d_ws;                       // 8 MiB
  short* wqb = xb  + (size_t)BS_ * H_;             // 128 KiB each
  short* wkb = wqb + H_ * H_;
  short* wvb = wkb + H_ * H_;
  short* Qs  = wvb + H_ * H_;                      // 8 MiB
  short* Ks  = Qs  + (size_t)BS_ * H_;             // 8 MiB
  short* VT  = Ks  + (size_t)BS_ * H_;             // 8 MiB
  short* P   = VT  + (size_t)BS_ * H_;             // 64 MiB (frag-linearized)
  float* den = (float*)(P + (size_t)B_ * S_ * S_); // 64 KiB
  float* rcp = den + BS_;                          // 64 KiB
  float* outp = (float*)d_out;

  cvt_bf16<<<1024, 256, 0, stream>>>(x, Wq, Wk, Wv, xb, wqb, wkb, wvb);
  qkv_proj<<<dim3(BS_ / 64, 3), 256, 0, stream>>>(xb, wqb, bq, wkb, bk, wvb, bv, Qs, Ks, VT);
  zero_den<<<64, 256, 0, stream>>>(den);
  zero_out<<<4096, 256, 0, stream>>>(outp);
  scores<<<2048, 256, 0, stream>>>(Qs, Ks, P, den);
  den_rcp<<<64, 256, 0, stream>>>(den, rcp);
  vscale<<<4096, 256, 0, stream>>>(VT, rcp);
  pv<<<2048, 256, 0, stream>>>(P, VT, outp);
}

// Round 6
// 265.282 us; speedup vs baseline: 1.4733x; 1.4733x over previous
//
#include <hip/hip_runtime.h>
#include <hip/hip_bf16.h>

#define B_ 8
#define S_ 2048
#define H_ 256
#define BS_ (B_*S_)

typedef __attribute__((ext_vector_type(8))) short bf16x8;
typedef __attribute__((ext_vector_type(4))) short bf16x4;
typedef __attribute__((ext_vector_type(4))) float f32x4;

static __device__ inline short f2bf(float f) {
  union { float f; unsigned int u; } a; a.f = f;
  unsigned int u = a.u;
  unsigned int r = (u + 0x7fffu + ((u >> 16) & 1u)) >> 16;
  return (short)r;
}

static __device__ inline float bf2f(short s) {
  union { float f; unsigned int u; } a;
  a.u = ((unsigned int)(unsigned short)s) << 16;
  return a.f;
}

static __device__ inline f32x4 mfma16(bf16x8 a, bf16x8 b, f32x4 c) {
  return __builtin_amdgcn_mfma_f32_16x16x32_bf16(a, b, c, 0, 0, 0);
}

// async global(16B/lane) -> LDS(wave-uniform base + lane*16)
static __device__ inline void gl_lds16(const short* g, short* l) {
  __builtin_amdgcn_global_load_lds(
      (const __attribute__((address_space(1))) void*)g,
      (__attribute__((address_space(3))) void*)l, 16, 0, 0);
}

// ---------------------------------------------------------------------------
// Kernel 0: fp32 -> bf16 conversion of x, Wq, Wk, Wv into workspace.
// ---------------------------------------------------------------------------
#define NX4 (BS_ * H_ / 4)
#define NW4 (H_ * H_ / 4)
#define NTOT4 (NX4 + 3 * NW4)

__global__ __launch_bounds__(256) void cvt_bf16(
    const float* __restrict__ x,
    const float* __restrict__ Wq, const float* __restrict__ Wk,
    const float* __restrict__ Wv,
    short* __restrict__ xb, short* __restrict__ wqb,
    short* __restrict__ wkb, short* __restrict__ wvb)
{
  int stride = gridDim.x * blockDim.x;
  for (int i = blockIdx.x * blockDim.x + threadIdx.x; i < NTOT4; i += stride) {
    const float* src; short* dst; int off;
    if (i < NX4) { src = x; dst = xb; off = i; }
    else {
      int j = i - NX4;
      int w = j >> 14;
      off = j & (NW4 - 1);
      src = (w == 0) ? Wq : (w == 1) ? Wk : Wv;
      dst = (w == 0) ? wqb : (w == 1) ? wkb : wvb;
    }
    float4 v = *(const float4*)(src + off * 4);
    bf16x4 p;
    p[0] = f2bf(v.x); p[1] = f2bf(v.y); p[2] = f2bf(v.z); p[3] = f2bf(v.w);
    *(bf16x4*)(dst + off * 4) = p;
  }
}

// ---------------------------------------------------------------------------
// Kernel 1: Q/K row-major + V transposed [b][h][k]. grid (BS/64, 3), block 256.
// ---------------------------------------------------------------------------
__global__ __launch_bounds__(256) void qkv_proj(
    const short* __restrict__ x,
    const short* __restrict__ Wq, const float* __restrict__ bq,
    const short* __restrict__ Wk, const float* __restrict__ bk,
    const short* __restrict__ Wv, const float* __restrict__ bv,
    short* __restrict__ Qo, short* __restrict__ Ko, short* __restrict__ VTo)
{
  const int tid  = threadIdx.x;
  const int wave = tid >> 6;
  const int lane = tid & 63;
  const int quad = lane >> 4;
  const int l16  = lane & 15;
  const int y    = blockIdx.y;

  const short* W    = (y == 0) ? Wq : (y == 1) ? Wk : Wv;
  const float* bias = (y == 0) ? bq : (y == 1) ? bk : bv;
  const int s0 = blockIdx.x * 64 + wave * 16;

  f32x4 zero = {0.f, 0.f, 0.f, 0.f};
  f32x4 acc[16];
#pragma unroll
  for (int i = 0; i < 16; i++) acc[i] = zero;

  const short* xrow = x + (s0 + l16) * H_ + quad * 8;
#pragma unroll
  for (int ks = 0; ks < 8; ks++) {
    bf16x8 a = *(const bf16x8*)(xrow + ks * 32);
#pragma unroll
    for (int nf = 0; nf < 16; nf++) {
      bf16x8 bb = *(const bf16x8*)(W + (nf * 16 + l16) * H_ + ks * 32 + quad * 8);
      acc[nf] = mfma16(a, bb, acc[nf]);
    }
  }

  if (y < 2) {
    short* dst = (y == 0) ? Qo : Ko;
#pragma unroll
    for (int nf = 0; nf < 16; nf++) {
      int col = nf * 16 + l16;
      float bvl = bias[col];
#pragma unroll
      for (int r = 0; r < 4; r++) {
        int row = s0 + quad * 4 + r;
        dst[row * H_ + col] = f2bf(acc[nf][r] + bvl);
      }
    }
  } else {
    int row0  = s0 + quad * 4;
    int b_idx = row0 >> 11;
    int k0    = row0 & (S_ - 1);
#pragma unroll
    for (int nf = 0; nf < 16; nf++) {
      int col = nf * 16 + l16;
      float bvl = bias[col];
      bf16x4 pk;
#pragma unroll
      for (int r = 0; r < 4; r++) pk[r] = f2bf(acc[nf][r] + bvl);
      *(bf16x4*)(VTo + (size_t)b_idx * H_ * S_ + (size_t)col * S_ + k0) = pk;
    }
  }
}

// ---------------------------------------------------------------------------
// Kernel 2a: zero the denominator accumulator (ws is poisoned 0xAA).
// ---------------------------------------------------------------------------
__global__ __launch_bounds__(256) void zero_den(float* __restrict__ den)
{
  int i = blockIdx.x * 256 + threadIdx.x;
  if (i < BS_) den[i] = 0.f;
}

// ---------------------------------------------------------------------------
// Kernel 2b: P = exp(QK^T/256) in A-FRAGMENT-LINEARIZED layout:
//   Pf[b][q/16][k/32][lane][8]  (tile = 512 bf16 = 1 KiB).
// Computed as S^T = K.Q^T; den[b][k] += row-sums.
// grid 2048 = b(8) x kt(16) x qt(16), block 256.
// ---------------------------------------------------------------------------
__global__ __launch_bounds__(256) void scores(
    const short* __restrict__ Q, const short* __restrict__ K,
    short* __restrict__ Pf, float* __restrict__ den)
{
  const int tid  = threadIdx.x;
  const int wave = tid >> 6;
  const int lane = tid & 63;
  const int quad = lane >> 4;
  const int l16  = lane & 15;
  const int qt = blockIdx.x & 15;
  const int kt = (blockIdx.x >> 4) & 15;
  const int b  = blockIdx.x >> 8;

  const short* Qb = Q + b * S_ * H_;
  const short* Kb = K + b * S_ * H_;

  const int krow0 = kt * 128 + wave * 32;
  const int qcol0 = qt * 128;
  const int kw    = krow0 >> 5;

  f32x4 zero = {0.f, 0.f, 0.f, 0.f};
  f32x4 acc[2][8];
#pragma unroll
  for (int i = 0; i < 2; i++)
#pragma unroll
    for (int j = 0; j < 8; j++) acc[i][j] = zero;

#pragma unroll
  for (int kk = 0; kk < 8; kk++) {
    bf16x8 a0 = *(const bf16x8*)(Kb + (krow0 + l16) * H_ + kk * 32 + quad * 8);
    bf16x8 a1 = *(const bf16x8*)(Kb + (krow0 + 16 + l16) * H_ + kk * 32 + quad * 8);
#pragma unroll
    for (int qf = 0; qf < 8; qf++) {
      bf16x8 bq = *(const bf16x8*)(Qb + (qcol0 + qf * 16 + l16) * H_ + kk * 32 + quad * 8);
      acc[0][qf] = mfma16(a0, bq, acc[0][qf]);
      acc[1][qf] = mfma16(a1, bq, acc[1][qf]);
    }
  }

  const int quadA = quad >> 1;
  const int j0    = (quad & 1) * 4;
  float rs[2][4] = {{0.f,0.f,0.f,0.f},{0.f,0.f,0.f,0.f}};
#pragma unroll
  for (int kf = 0; kf < 2; kf++) {
#pragma unroll
    for (int qf = 0; qf < 8; qf++) {
      bf16x4 pk;
#pragma unroll
      for (int r = 0; r < 4; r++) {
        float e = __expf(acc[kf][qf][r] * (1.0f / H_));
        rs[kf][r] += e;
        pk[r] = f2bf(e);
      }
      size_t tile = ((size_t)(b * 128 + qt * 8 + qf) << 6) + kw;
      *(bf16x4*)(Pf + (tile << 9) + ((2 * kf + quadA) * 16 + l16) * 8 + j0) = pk;
    }
  }

#pragma unroll
  for (int kf = 0; kf < 2; kf++) {
#pragma unroll
    for (int r = 0; r < 4; r++) {
      float v = rs[kf][r];
      v += __shfl_xor(v, 1, 64);
      v += __shfl_xor(v, 2, 64);
      v += __shfl_xor(v, 4, 64);
      v += __shfl_xor(v, 8, 64);
      if (l16 == 0)
        atomicAdd(&den[b * S_ + krow0 + kf * 16 + quad * 4 + r], v);
    }
  }
}

// ---------------------------------------------------------------------------
// Kernel 2c: rcp = 1/den.
// ---------------------------------------------------------------------------
__global__ __launch_bounds__(256) void den_rcp(
    const float* __restrict__ den, float* __restrict__ rcp)
{
  int i = blockIdx.x * 256 + threadIdx.x;
  if (i < BS_) rcp[i] = 1.0f / den[i];
}

// ---------------------------------------------------------------------------
// Kernel 2d: VT[b][h][k] *= rcp[b][k].
// ---------------------------------------------------------------------------
__global__ __launch_bounds__(256) void vscale(
    short* __restrict__ VT, const float* __restrict__ rcp)
{
  int i = blockIdx.x * 256 + threadIdx.x;
  int b  = i >> 17;
  int k0 = (i & 511) << 2;
  float4 rf = *(const float4*)(rcp + b * S_ + k0);
  bf16x4 v = *(bf16x4*)(VT + (size_t)i * 4);
  bf16x4 o;
  o[0] = f2bf(bf2f(v[0]) * rf.x);
  o[1] = f2bf(bf2f(v[1]) * rf.y);
  o[2] = f2bf(bf2f(v[2]) * rf.z);
  o[3] = f2bf(bf2f(v[3]) * rf.w);
  *(bf16x4*)(VT + (size_t)i * 4) = o;
}

// ---------------------------------------------------------------------------
// Kernel 3: out = Pf . Vs — m97-style LDS-staged GEMM.
// grid 512: bx = qt*16 + b*2 + hs (same-(b,hs) blocks -> same XCD -> V in L2).
// block 256 = 4 waves; wave owns 16 q x 128 h, K-loop BK=64, full K=2048.
// Both operands staged via global_load_lds into FRAG-LINEARIZED LDS regions:
//   vbuf region (n*2+kw): 512 shorts, lane l -> (h=n*16+(l&15), k=kw*32+(l>>4)*8)
//   abuf region (wave*2+kw): identity round-trip of a Pf tile.
// Every ds_read is one contiguous conflict-free 1 KiB ds_read_b128.
// ---------------------------------------------------------------------------
__global__ __launch_bounds__(256) void pv(
    const short* __restrict__ Pf, const short* __restrict__ VTs,
    float* __restrict__ out)
{
  const int tid  = threadIdx.x;
  const int wave = tid >> 6;
  const int lane = tid & 63;
  const int quad = lane >> 4;
  const int l16  = lane & 15;
  const int bx = blockIdx.x;
  const int qt = bx >> 4;
  const int b  = (bx >> 1) & 7;
  const int hs = bx & 1;

  __shared__ short vbuf[16 * 512];   // 16 KiB
  __shared__ short abuf[8 * 512];    // 8 KiB

  const int qt16 = qt * 4 + wave;
  const short* VTb = VTs + (size_t)b * H_ * S_ + (size_t)(hs * 128) * S_;
  const size_t tilebase = ((size_t)(b * 128 + qt16) * 64) << 9;

  f32x4 zero = {0.f, 0.f, 0.f, 0.f};
  f32x4 acc[8];
#pragma unroll
  for (int i = 0; i < 8; i++) acc[i] = zero;

  for (int kc = 0; kc < S_; kc += 64) {
    // stage V: 16 regions, 4 per wave
#pragma unroll
    for (int i = 0; i < 4; i++) {
      int id = wave * 4 + i;
      int n  = id >> 1;
      int kw = id & 1;
      const short* g = VTb + (size_t)(n * 16 + l16) * S_ + kc + kw * 32 + quad * 8;
      gl_lds16(g, vbuf + id * 512);
    }
    // stage A: 2 regions per wave (identity round-trip of Pf tiles)
#pragma unroll
    for (int kwi = 0; kwi < 2; kwi++) {
      const short* g = Pf + tilebase + (size_t)((kc >> 5) + kwi) * 512 + lane * 8;
      gl_lds16(g, abuf + (wave * 2 + kwi) * 512);
    }
    __syncthreads();
#pragma unroll
    for (int kw = 0; kw < 2; kw++) {
      bf16x8 a = *(const bf16x8*)(abuf + (wave * 2 + kw) * 512 + lane * 8);
#pragma unroll
      for (int n = 0; n < 8; n++) {
        bf16x8 vb = *(const bf16x8*)(vbuf + (n * 2 + kw) * 512 + lane * 8);
        acc[n] = mfma16(a, vb, acc[n]);
      }
    }
    __syncthreads();
  }

  const int q0 = qt16 * 16;
#pragma unroll
  for (int n = 0; n < 8; n++) {
    int col = hs * 128 + n * 16 + l16;
#pragma unroll
    for (int r = 0; r < 4; r++) {
      int q = q0 + quad * 4 + r;
      out[((size_t)b * S_ + q) * H_ + col] = acc[n][r];
    }
  }
}

extern "C" void kernel_launch(void* const* d_in, const int* in_sizes, int n_in,
                              void* d_out, int out_size, void* d_ws, size_t ws_size,
                              hipStream_t stream) {
  const float* x  = (const float*)d_in[0];
  const float* Wq = (const float*)d_in[1];
  const float* bq = (const float*)d_in[2];
  const float* Wk = (const float*)d_in[3];
  const float* bk = (const float*)d_in[4];
  const float* Wv = (const float*)d_in[5];
  const float* bv = (const float*)d_in[6];

  short* xb  = (short*)d_ws;                       // 8 MiB
  short* wqb = xb  + (size_t)BS_ * H_;             // 128 KiB each
  short* wkb = wqb + H_ * H_;
  short* wvb = wkb + H_ * H_;
  short* Qs  = wvb + H_ * H_;                      // 8 MiB
  short* Ks  = Qs  + (size_t)BS_ * H_;             // 8 MiB
  short* VT  = Ks  + (size_t)BS_ * H_;             // 8 MiB
  short* P   = VT  + (size_t)BS_ * H_;             // 64 MiB (frag-linearized)
  float* den = (float*)(P + (size_t)B_ * S_ * S_); // 64 KiB
  float* rcp = den + BS_;                          // 64 KiB
  float* outp = (float*)d_out;

  cvt_bf16<<<1024, 256, 0, stream>>>(x, Wq, Wk, Wv, xb, wqb, wkb, wvb);
  qkv_proj<<<dim3(BS_ / 64, 3), 256, 0, stream>>>(xb, wqb, bq, wkb, bk, wvb, bv, Qs, Ks, VT);
  zero_den<<<64, 256, 0, stream>>>(den);
  scores<<<2048, 256, 0, stream>>>(Qs, Ks, P, den);
  den_rcp<<<64, 256, 0, stream>>>(den, rcp);
  vscale<<<4096, 256, 0, stream>>>(VT, rcp);
  pv<<<512, 256, 0, stream>>>(P, VT, outp);
}

// Round 7
// 225.456 us; speedup vs baseline: 1.7336x; 1.1766x over previous
//
#include <hip/hip_runtime.h>
#include <hip/hip_bf16.h>

#define B_ 8
#define S_ 2048
#define H_ 256
#define BS_ (B_*S_)

typedef __attribute__((ext_vector_type(8))) short bf16x8;
typedef __attribute__((ext_vector_type(4))) short bf16x4;
typedef __attribute__((ext_vector_type(4))) float f32x4;

static __device__ inline short f2bf(float f) {
  union { float f; unsigned int u; } a; a.f = f;
  unsigned int u = a.u;
  unsigned int r = (u + 0x7fffu + ((u >> 16) & 1u)) >> 16;
  return (short)r;
}

static __device__ inline float bf2f(short s) {
  union { float f; unsigned int u; } a;
  a.u = ((unsigned int)(unsigned short)s) << 16;
  return a.f;
}

static __device__ inline f32x4 mfma16(bf16x8 a, bf16x8 b, f32x4 c) {
  return __builtin_amdgcn_mfma_f32_16x16x32_bf16(a, b, c, 0, 0, 0);
}

// async global(16B/lane) -> LDS(wave-uniform base + lane*16)
static __device__ inline void gl_lds16(const short* g, short* l) {
  __builtin_amdgcn_global_load_lds(
      (const __attribute__((address_space(1))) void*)g,
      (__attribute__((address_space(3))) void*)l, 16, 0, 0);
}

// ---------------------------------------------------------------------------
// Kernel 0: fp32 -> bf16 conversion of x, Wq, Wk, Wv into workspace.
// ---------------------------------------------------------------------------
#define NX4 (BS_ * H_ / 4)
#define NW4 (H_ * H_ / 4)
#define NTOT4 (NX4 + 3 * NW4)

__global__ __launch_bounds__(256) void cvt_bf16(
    const float* __restrict__ x,
    const float* __restrict__ Wq, const float* __restrict__ Wk,
    const float* __restrict__ Wv,
    short* __restrict__ xb, short* __restrict__ wqb,
    short* __restrict__ wkb, short* __restrict__ wvb)
{
  int stride = gridDim.x * blockDim.x;
  for (int i = blockIdx.x * blockDim.x + threadIdx.x; i < NTOT4; i += stride) {
    const float* src; short* dst; int off;
    if (i < NX4) { src = x; dst = xb; off = i; }
    else {
      int j = i - NX4;
      int w = j >> 14;
      off = j & (NW4 - 1);
      src = (w == 0) ? Wq : (w == 1) ? Wk : Wv;
      dst = (w == 0) ? wqb : (w == 1) ? wkb : wvb;
    }
    float4 v = *(const float4*)(src + off * 4);
    bf16x4 p;
    p[0] = f2bf(v.x); p[1] = f2bf(v.y); p[2] = f2bf(v.z); p[3] = f2bf(v.w);
    *(bf16x4*)(dst + off * 4) = p;
  }
}

// ---------------------------------------------------------------------------
// Kernel 1: Q/K row-major + V transposed [b][h][k]. grid (BS/64, 3), block 256.
// ---------------------------------------------------------------------------
__global__ __launch_bounds__(256) void qkv_proj(
    const short* __restrict__ x,
    const short* __restrict__ Wq, const float* __restrict__ bq,
    const short* __restrict__ Wk, const float* __restrict__ bk,
    const short* __restrict__ Wv, const float* __restrict__ bv,
    short* __restrict__ Qo, short* __restrict__ Ko, short* __restrict__ VTo)
{
  const int tid  = threadIdx.x;
  const int wave = tid >> 6;
  const int lane = tid & 63;
  const int quad = lane >> 4;
  const int l16  = lane & 15;
  const int y    = blockIdx.y;

  const short* W    = (y == 0) ? Wq : (y == 1) ? Wk : Wv;
  const float* bias = (y == 0) ? bq : (y == 1) ? bk : bv;
  const int s0 = blockIdx.x * 64 + wave * 16;

  f32x4 zero = {0.f, 0.f, 0.f, 0.f};
  f32x4 acc[16];
#pragma unroll
  for (int i = 0; i < 16; i++) acc[i] = zero;

  const short* xrow = x + (s0 + l16) * H_ + quad * 8;
#pragma unroll
  for (int ks = 0; ks < 8; ks++) {
    bf16x8 a = *(const bf16x8*)(xrow + ks * 32);
#pragma unroll
    for (int nf = 0; nf < 16; nf++) {
      bf16x8 bb = *(const bf16x8*)(W + (nf * 16 + l16) * H_ + ks * 32 + quad * 8);
      acc[nf] = mfma16(a, bb, acc[nf]);
    }
  }

  if (y < 2) {
    short* dst = (y == 0) ? Qo : Ko;
#pragma unroll
    for (int nf = 0; nf < 16; nf++) {
      int col = nf * 16 + l16;
      float bvl = bias[col];
#pragma unroll
      for (int r = 0; r < 4; r++) {
        int row = s0 + quad * 4 + r;
        dst[row * H_ + col] = f2bf(acc[nf][r] + bvl);
      }
    }
  } else {
    int row0  = s0 + quad * 4;
    int b_idx = row0 >> 11;
    int k0    = row0 & (S_ - 1);
#pragma unroll
    for (int nf = 0; nf < 16; nf++) {
      int col = nf * 16 + l16;
      float bvl = bias[col];
      bf16x4 pk;
#pragma unroll
      for (int r = 0; r < 4; r++) pk[r] = f2bf(acc[nf][r] + bvl);
      *(bf16x4*)(VTo + (size_t)b_idx * H_ * S_ + (size_t)col * S_ + k0) = pk;
    }
  }
}

// ---------------------------------------------------------------------------
// Kernel 2a: zero the denominator accumulator (ws is poisoned 0xAA).
// ---------------------------------------------------------------------------
__global__ __launch_bounds__(256) void zero_den(float* __restrict__ den)
{
  int i = blockIdx.x * 256 + threadIdx.x;
  if (i < BS_) den[i] = 0.f;
}

// ---------------------------------------------------------------------------
// Kernel 2b: P = exp(QK^T/256) in A-FRAGMENT-LINEARIZED layout:
//   Pf[b][q/16][k/32][lane][8]  (tile = 512 bf16 = 1 KiB).
// Computed as S^T = K.Q^T, m97-style LDS staging of both operands:
//   per 32-wide H-chunk, 8 K-regions + 8 Q-regions (16 rows x 32 H = 1 KiB),
//   staged via global_load_lds; every ds_read is a contiguous 1 KiB b128.
// den[b][k] += row-sums. grid 2048 = b(8) x kt(16) x qt(16), block 256.
// ---------------------------------------------------------------------------
__global__ __launch_bounds__(256) void scores(
    const short* __restrict__ Q, const short* __restrict__ K,
    short* __restrict__ Pf, float* __restrict__ den)
{
  const int tid  = threadIdx.x;
  const int wave = tid >> 6;
  const int lane = tid & 63;
  const int quad = lane >> 4;
  const int l16  = lane & 15;
  const int qt = blockIdx.x & 15;
  const int kt = (blockIdx.x >> 4) & 15;
  const int b  = blockIdx.x >> 8;

  const short* Qb = Q + b * S_ * H_;
  const short* Kb = K + b * S_ * H_;

  const int krow0 = kt * 128 + wave * 32;
  const int qcol0 = qt * 128;
  const int kw    = krow0 >> 5;

  __shared__ short kbuf[8 * 512];   // 8 KiB: K rows (kt*128 .. +128) x 32 H
  __shared__ short qbuf[8 * 512];   // 8 KiB: Q rows (qt*128 .. +128) x 32 H

  f32x4 zero = {0.f, 0.f, 0.f, 0.f};
  f32x4 acc[2][8];
#pragma unroll
  for (int i = 0; i < 2; i++)
#pragma unroll
    for (int j = 0; j < 8; j++) acc[i][j] = zero;

  for (int ch = 0; ch < 8; ch++) {
    // stage: wave w handles K-regions {2w, 2w+1} and Q-regions {2w, 2w+1}
#pragma unroll
    for (int i = 0; i < 2; i++) {
      int r = wave * 2 + i;
      gl_lds16(Kb + (kt * 128 + r * 16 + l16) * H_ + ch * 32 + quad * 8,
               kbuf + r * 512);
      gl_lds16(Qb + (qcol0 + r * 16 + l16) * H_ + ch * 32 + quad * 8,
               qbuf + r * 512);
    }
    __syncthreads();
    bf16x8 a0 = *(const bf16x8*)(kbuf + (wave * 2 + 0) * 512 + lane * 8);
    bf16x8 a1 = *(const bf16x8*)(kbuf + (wave * 2 + 1) * 512 + lane * 8);
#pragma unroll
    for (int qf = 0; qf < 8; qf++) {
      bf16x8 bq = *(const bf16x8*)(qbuf + qf * 512 + lane * 8);
      acc[0][qf] = mfma16(a0, bq, acc[0][qf]);
      acc[1][qf] = mfma16(a1, bq, acc[1][qf]);
    }
    __syncthreads();
  }

  const int quadA = quad >> 1;
  const int j0    = (quad & 1) * 4;
  float rs[2][4] = {{0.f,0.f,0.f,0.f},{0.f,0.f,0.f,0.f}};
#pragma unroll
  for (int kf = 0; kf < 2; kf++) {
#pragma unroll
    for (int qf = 0; qf < 8; qf++) {
      bf16x4 pk;
#pragma unroll
      for (int r = 0; r < 4; r++) {
        float e = __expf(acc[kf][qf][r] * (1.0f / H_));
        rs[kf][r] += e;
        pk[r] = f2bf(e);
      }
      size_t tile = ((size_t)(b * 128 + qt * 8 + qf) << 6) + kw;
      *(bf16x4*)(Pf + (tile << 9) + ((2 * kf + quadA) * 16 + l16) * 8 + j0) = pk;
    }
  }

#pragma unroll
  for (int kf = 0; kf < 2; kf++) {
#pragma unroll
    for (int r = 0; r < 4; r++) {
      float v = rs[kf][r];
      v += __shfl_xor(v, 1, 64);
      v += __shfl_xor(v, 2, 64);
      v += __shfl_xor(v, 4, 64);
      v += __shfl_xor(v, 8, 64);
      if (l16 == 0)
        atomicAdd(&den[b * S_ + krow0 + kf * 16 + quad * 4 + r], v);
    }
  }
}

// ---------------------------------------------------------------------------
// Kernel 2c: rcp = 1/den.
// ---------------------------------------------------------------------------
__global__ __launch_bounds__(256) void den_rcp(
    const float* __restrict__ den, float* __restrict__ rcp)
{
  int i = blockIdx.x * 256 + threadIdx.x;
  if (i < BS_) rcp[i] = 1.0f / den[i];
}

// ---------------------------------------------------------------------------
// Kernel 2d: VT[b][h][k] *= rcp[b][k].
// ---------------------------------------------------------------------------
__global__ __launch_bounds__(256) void vscale(
    short* __restrict__ VT, const float* __restrict__ rcp)
{
  int i = blockIdx.x * 256 + threadIdx.x;
  int b  = i >> 17;
  int k0 = (i & 511) << 2;
  float4 rf = *(const float4*)(rcp + b * S_ + k0);
  bf16x4 v = *(bf16x4*)(VT + (size_t)i * 4);
  bf16x4 o;
  o[0] = f2bf(bf2f(v[0]) * rf.x);
  o[1] = f2bf(bf2f(v[1]) * rf.y);
  o[2] = f2bf(bf2f(v[2]) * rf.z);
  o[3] = f2bf(bf2f(v[3]) * rf.w);
  *(bf16x4*)(VT + (size_t)i * 4) = o;
}

// ---------------------------------------------------------------------------
// Kernel 3: out = Pf . Vs — m97-style LDS-staged GEMM.
// grid 512: bx = qt*16 + b*2 + hs (same-(b,hs) blocks -> same XCD -> V in L2).
// ---------------------------------------------------------------------------
__global__ __launch_bounds__(256) void pv(
    const short* __restrict__ Pf, const short* __restrict__ VTs,
    float* __restrict__ out)
{
  const int tid  = threadIdx.x;
  const int wave = tid >> 6;
  const int lane = tid & 63;
  const int quad = lane >> 4;
  const int l16  = lane & 15;
  const int bx = blockIdx.x;
  const int qt = bx >> 4;
  const int b  = (bx >> 1) & 7;
  const int hs = bx & 1;

  __shared__ short vbuf[16 * 512];   // 16 KiB
  __shared__ short abuf[8 * 512];    // 8 KiB

  const int qt16 = qt * 4 + wave;
  const short* VTb = VTs + (size_t)b * H_ * S_ + (size_t)(hs * 128) * S_;
  const size_t tilebase = ((size_t)(b * 128 + qt16) * 64) << 9;

  f32x4 zero = {0.f, 0.f, 0.f, 0.f};
  f32x4 acc[8];
#pragma unroll
  for (int i = 0; i < 8; i++) acc[i] = zero;

  for (int kc = 0; kc < S_; kc += 64) {
    // stage V: 16 regions, 4 per wave
#pragma unroll
    for (int i = 0; i < 4; i++) {
      int id = wave * 4 + i;
      int n  = id >> 1;
      int kw = id & 1;
      const short* g = VTb + (size_t)(n * 16 + l16) * S_ + kc + kw * 32 + quad * 8;
      gl_lds16(g, vbuf + id * 512);
    }
    // stage A: 2 regions per wave (identity round-trip of Pf tiles)
#pragma unroll
    for (int kwi = 0; kwi < 2; kwi++) {
      const short* g = Pf + tilebase + (size_t)((kc >> 5) + kwi) * 512 + lane * 8;
      gl_lds16(g, abuf + (wave * 2 + kwi) * 512);
    }
    __syncthreads();
#pragma unroll
    for (int kw = 0; kw < 2; kw++) {
      bf16x8 a = *(const bf16x8*)(abuf + (wave * 2 + kw) * 512 + lane * 8);
#pragma unroll
      for (int n = 0; n < 8; n++) {
        bf16x8 vb = *(const bf16x8*)(vbuf + (n * 2 + kw) * 512 + lane * 8);
        acc[n] = mfma16(a, vb, acc[n]);
      }
    }
    __syncthreads();
  }

  const int q0 = qt16 * 16;
#pragma unroll
  for (int n = 0; n < 8; n++) {
    int col = hs * 128 + n * 16 + l16;
#pragma unroll
    for (int r = 0; r < 4; r++) {
      int q = q0 + quad * 4 + r;
      out[((size_t)b * S_ + q) * H_ + col] = acc[n][r];
    }
  }
}

extern "C" void kernel_launch(void* const* d_in, const int* in_sizes, int n_in,
                              void* d_out, int out_size, void* d_ws, size_t ws_size,
                              hipStream_t stream) {
  const float* x  = (const float*)d_in[0];
  const float* Wq = (const float*)d_in[1];
  const float* bq = (const float*)d_in[2];
  const float* Wk = (const float*)d_in[3];
  const float* bk = (const float*)d_in[4];
  const float* Wv = (const float*)d_in[5];
  const float* bv = (const float*)d_in[6];

  short* xb  = (short*)d_ws;                       // 8 MiB
  short* wqb = xb  + (size_t)BS_ * H_;             // 128 KiB each
  short* wkb = wqb + H_ * H_;
  short* wvb = wkb + H_ * H_;
  short* Qs  = wvb + H_ * H_;                      // 8 MiB
  short* Ks  = Qs  + (size_t)BS_ * H_;             // 8 MiB
  short* VT  = Ks  + (size_t)BS_ * H_;             // 8 MiB
  short* P   = VT  + (size_t)BS_ * H_;             // 64 MiB (frag-linearized)
  float* den = (float*)(P + (size_t)B_ * S_ * S_); // 64 KiB
  float* rcp = den + BS_;                          // 64 KiB
  float* outp = (float*)d_out;

  cvt_bf16<<<1024, 256, 0, stream>>>(x, Wq, Wk, Wv, xb, wqb, wkb, wvb);
  qkv_proj<<<dim3(BS_ / 64, 3), 256, 0, stream>>>(xb, wqb, bq, wkb, bk, wvb, bv, Qs, Ks, VT);
  zero_den<<<64, 256, 0, stream>>>(den);
  scores<<<2048, 256, 0, stream>>>(Qs, Ks, P, den);
  den_rcp<<<64, 256, 0, stream>>>(den, rcp);
  vscale<<<4096, 256, 0, stream>>>(VT, rcp);
  pv<<<512, 256, 0, stream>>>(P, VT, outp);
}

// Round 8
// 198.247 us; speedup vs baseline: 1.9715x; 1.1372x over previous
//
#include <hip/hip_runtime.h>
#include <hip/hip_bf16.h>

#define B_ 8
#define S_ 2048
#define H_ 256
#define BS_ (B_*S_)

typedef __attribute__((ext_vector_type(8))) short bf16x8;
typedef __attribute__((ext_vector_type(4))) short bf16x4;
typedef __attribute__((ext_vector_type(4))) float f32x4;

static __device__ inline short f2bf(float f) {
  union { float f; unsigned int u; } a; a.f = f;
  unsigned int u = a.u;
  unsigned int r = (u + 0x7fffu + ((u >> 16) & 1u)) >> 16;
  return (short)r;
}

static __device__ inline float bf2f(short s) {
  union { float f; unsigned int u; } a;
  a.u = ((unsigned int)(unsigned short)s) << 16;
  return a.f;
}

static __device__ inline f32x4 mfma16(bf16x8 a, bf16x8 b, f32x4 c) {
  return __builtin_amdgcn_mfma_f32_16x16x32_bf16(a, b, c, 0, 0, 0);
}

// async global(16B/lane) -> LDS(wave-uniform base + lane*16)
static __device__ inline void gl_lds16(const short* g, short* l) {
  __builtin_amdgcn_global_load_lds(
      (const __attribute__((address_space(1))) void*)g,
      (__attribute__((address_space(3))) void*)l, 16, 0, 0);
}

// ---------------------------------------------------------------------------
// Kernel 0: fp32 -> bf16 conversion of x, Wq, Wk, Wv into workspace.
// ---------------------------------------------------------------------------
#define NX4 (BS_ * H_ / 4)
#define NW4 (H_ * H_ / 4)
#define NTOT4 (NX4 + 3 * NW4)

__global__ __launch_bounds__(256) void cvt_bf16(
    const float* __restrict__ x,
    const float* __restrict__ Wq, const float* __restrict__ Wk,
    const float* __restrict__ Wv,
    short* __restrict__ xb, short* __restrict__ wqb,
    short* __restrict__ wkb, short* __restrict__ wvb)
{
  int stride = gridDim.x * blockDim.x;
  for (int i = blockIdx.x * blockDim.x + threadIdx.x; i < NTOT4; i += stride) {
    const float* src; short* dst; int off;
    if (i < NX4) { src = x; dst = xb; off = i; }
    else {
      int j = i - NX4;
      int w = j >> 14;
      off = j & (NW4 - 1);
      src = (w == 0) ? Wq : (w == 1) ? Wk : Wv;
      dst = (w == 0) ? wqb : (w == 1) ? wkb : wvb;
    }
    float4 v = *(const float4*)(src + off * 4);
    bf16x4 p;
    p[0] = f2bf(v.x); p[1] = f2bf(v.y); p[2] = f2bf(v.z); p[3] = f2bf(v.w);
    *(bf16x4*)(dst + off * 4) = p;
  }
}

// ---------------------------------------------------------------------------
// Kernel 1: Q/K row-major + V transposed [b][h][k]. grid (BS/64, 3), block 256.
// m97-style LDS staging: per 32-wide K-chunk, 16 W-regions + 4 X-regions
// (16 rows x 32 = 1 KiB each) via global_load_lds; all ds_reads contiguous.
// ---------------------------------------------------------------------------
__global__ __launch_bounds__(256) void qkv_proj(
    const short* __restrict__ x,
    const short* __restrict__ Wq, const float* __restrict__ bq,
    const short* __restrict__ Wk, const float* __restrict__ bk,
    const short* __restrict__ Wv, const float* __restrict__ bv,
    short* __restrict__ Qo, short* __restrict__ Ko, short* __restrict__ VTo)
{
  const int tid  = threadIdx.x;
  const int wave = tid >> 6;
  const int lane = tid & 63;
  const int quad = lane >> 4;
  const int l16  = lane & 15;
  const int y    = blockIdx.y;

  const short* W    = (y == 0) ? Wq : (y == 1) ? Wk : Wv;
  const float* bias = (y == 0) ? bq : (y == 1) ? bk : bv;
  const int sblk = blockIdx.x * 64;
  const int s0   = sblk + wave * 16;

  __shared__ short wbuf[16 * 512];   // 16 KiB: all 256 W-rows x 32-K chunk
  __shared__ short xbuf[4 * 512];    // 4 KiB: 64 X-rows x 32-K chunk

  f32x4 zero = {0.f, 0.f, 0.f, 0.f};
  f32x4 acc[16];
#pragma unroll
  for (int i = 0; i < 16; i++) acc[i] = zero;

  for (int ch = 0; ch < 8; ch++) {
    // stage W: wave w handles regions {4w..4w+3}; X: region w
#pragma unroll
    for (int i = 0; i < 4; i++) {
      int r = wave * 4 + i;
      gl_lds16(W + (r * 16 + l16) * H_ + ch * 32 + quad * 8, wbuf + r * 512);
    }
    gl_lds16(x + (s0 + l16) * H_ + ch * 32 + quad * 8, xbuf + wave * 512);
    __syncthreads();
    bf16x8 a = *(const bf16x8*)(xbuf + wave * 512 + lane * 8);
#pragma unroll
    for (int nf = 0; nf < 16; nf++) {
      bf16x8 bb = *(const bf16x8*)(wbuf + nf * 512 + lane * 8);
      acc[nf] = mfma16(a, bb, acc[nf]);
    }
    __syncthreads();
  }

  if (y < 2) {
    short* dst = (y == 0) ? Qo : Ko;
#pragma unroll
    for (int nf = 0; nf < 16; nf++) {
      int col = nf * 16 + l16;
      float bvl = bias[col];
#pragma unroll
      for (int r = 0; r < 4; r++) {
        int row = s0 + quad * 4 + r;
        dst[row * H_ + col] = f2bf(acc[nf][r] + bvl);
      }
    }
  } else {
    int row0  = s0 + quad * 4;
    int b_idx = row0 >> 11;
    int k0    = row0 & (S_ - 1);
#pragma unroll
    for (int nf = 0; nf < 16; nf++) {
      int col = nf * 16 + l16;
      float bvl = bias[col];
      bf16x4 pk;
#pragma unroll
      for (int r = 0; r < 4; r++) pk[r] = f2bf(acc[nf][r] + bvl);
      *(bf16x4*)(VTo + (size_t)b_idx * H_ * S_ + (size_t)col * S_ + k0) = pk;
    }
  }
}

// ---------------------------------------------------------------------------
// Kernel 2a: zero the denominator accumulator (ws is poisoned 0xAA).
// ---------------------------------------------------------------------------
__global__ __launch_bounds__(256) void zero_den(float* __restrict__ den)
{
  int i = blockIdx.x * 256 + threadIdx.x;
  if (i < BS_) den[i] = 0.f;
}

// ---------------------------------------------------------------------------
// Kernel 2b: P = exp(QK^T/256) in A-FRAGMENT-LINEARIZED layout:
//   Pf[b][q/16][k/32][lane][8]  (tile = 512 bf16 = 1 KiB).
// Computed as S^T = K.Q^T, m97-style LDS staging of both operands.
// den[b][k] += row-sums. grid 2048 = b(8) x kt(16) x qt(16), block 256.
// ---------------------------------------------------------------------------
__global__ __launch_bounds__(256) void scores(
    const short* __restrict__ Q, const short* __restrict__ K,
    short* __restrict__ Pf, float* __restrict__ den)
{
  const int tid  = threadIdx.x;
  const int wave = tid >> 6;
  const int lane = tid & 63;
  const int quad = lane >> 4;
  const int l16  = lane & 15;
  const int qt = blockIdx.x & 15;
  const int kt = (blockIdx.x >> 4) & 15;
  const int b  = blockIdx.x >> 8;

  const short* Qb = Q + b * S_ * H_;
  const short* Kb = K + b * S_ * H_;

  const int krow0 = kt * 128 + wave * 32;
  const int qcol0 = qt * 128;
  const int kw    = krow0 >> 5;

  __shared__ short kbuf[8 * 512];   // 8 KiB
  __shared__ short qbuf[8 * 512];   // 8 KiB

  f32x4 zero = {0.f, 0.f, 0.f, 0.f};
  f32x4 acc[2][8];
#pragma unroll
  for (int i = 0; i < 2; i++)
#pragma unroll
    for (int j = 0; j < 8; j++) acc[i][j] = zero;

  for (int ch = 0; ch < 8; ch++) {
#pragma unroll
    for (int i = 0; i < 2; i++) {
      int r = wave * 2 + i;
      gl_lds16(Kb + (kt * 128 + r * 16 + l16) * H_ + ch * 32 + quad * 8,
               kbuf + r * 512);
      gl_lds16(Qb + (qcol0 + r * 16 + l16) * H_ + ch * 32 + quad * 8,
               qbuf + r * 512);
    }
    __syncthreads();
    bf16x8 a0 = *(const bf16x8*)(kbuf + (wave * 2 + 0) * 512 + lane * 8);
    bf16x8 a1 = *(const bf16x8*)(kbuf + (wave * 2 + 1) * 512 + lane * 8);
#pragma unroll
    for (int qf = 0; qf < 8; qf++) {
      bf16x8 bq = *(const bf16x8*)(qbuf + qf * 512 + lane * 8);
      acc[0][qf] = mfma16(a0, bq, acc[0][qf]);
      acc[1][qf] = mfma16(a1, bq, acc[1][qf]);
    }
    __syncthreads();
  }

  const int quadA = quad >> 1;
  const int j0    = (quad & 1) * 4;
  float rs[2][4] = {{0.f,0.f,0.f,0.f},{0.f,0.f,0.f,0.f}};
#pragma unroll
  for (int kf = 0; kf < 2; kf++) {
#pragma unroll
    for (int qf = 0; qf < 8; qf++) {
      bf16x4 pk;
#pragma unroll
      for (int r = 0; r < 4; r++) {
        float e = __expf(acc[kf][qf][r] * (1.0f / H_));
        rs[kf][r] += e;
        pk[r] = f2bf(e);
      }
      size_t tile = ((size_t)(b * 128 + qt * 8 + qf) << 6) + kw;
      *(bf16x4*)(Pf + (tile << 9) + ((2 * kf + quadA) * 16 + l16) * 8 + j0) = pk;
    }
  }

#pragma unroll
  for (int kf = 0; kf < 2; kf++) {
#pragma unroll
    for (int r = 0; r < 4; r++) {
      float v = rs[kf][r];
      v += __shfl_xor(v, 1, 64);
      v += __shfl_xor(v, 2, 64);
      v += __shfl_xor(v, 4, 64);
      v += __shfl_xor(v, 8, 64);
      if (l16 == 0)
        atomicAdd(&den[b * S_ + krow0 + kf * 16 + quad * 4 + r], v);
    }
  }
}

// ---------------------------------------------------------------------------
// Kernel 2c: rcp = 1/den.
// ---------------------------------------------------------------------------
__global__ __launch_bounds__(256) void den_rcp(
    const float* __restrict__ den, float* __restrict__ rcp)
{
  int i = blockIdx.x * 256 + threadIdx.x;
  if (i < BS_) rcp[i] = 1.0f / den[i];
}

// ---------------------------------------------------------------------------
// Kernel 2d: VT[b][h][k] *= rcp[b][k].
// ---------------------------------------------------------------------------
__global__ __launch_bounds__(256) void vscale(
    short* __restrict__ VT, const float* __restrict__ rcp)
{
  int i = blockIdx.x * 256 + threadIdx.x;
  int b  = i >> 17;
  int k0 = (i & 511) << 2;
  float4 rf = *(const float4*)(rcp + b * S_ + k0);
  bf16x4 v = *(bf16x4*)(VT + (size_t)i * 4);
  bf16x4 o;
  o[0] = f2bf(bf2f(v[0]) * rf.x);
  o[1] = f2bf(bf2f(v[1]) * rf.y);
  o[2] = f2bf(bf2f(v[2]) * rf.z);
  o[3] = f2bf(bf2f(v[3]) * rf.w);
  *(bf16x4*)(VT + (size_t)i * 4) = o;
}

// ---------------------------------------------------------------------------
// Kernel 3: out = Pf . Vs — m97-style LDS-staged GEMM.
// grid 512: bx = qt*16 + b*2 + hs (same-(b,hs) blocks -> same XCD -> V in L2).
// ---------------------------------------------------------------------------
__global__ __launch_bounds__(256) void pv(
    const short* __restrict__ Pf, const short* __restrict__ VTs,
    float* __restrict__ out)
{
  const int tid  = threadIdx.x;
  const int wave = tid >> 6;
  const int lane = tid & 63;
  const int quad = lane >> 4;
  const int l16  = lane & 15;
  const int bx = blockIdx.x;
  const int qt = bx >> 4;
  const int b  = (bx >> 1) & 7;
  const int hs = bx & 1;

  __shared__ short vbuf[16 * 512];   // 16 KiB
  __shared__ short abuf[8 * 512];    // 8 KiB

  const int qt16 = qt * 4 + wave;
  const short* VTb = VTs + (size_t)b * H_ * S_ + (size_t)(hs * 128) * S_;
  const size_t tilebase = ((size_t)(b * 128 + qt16) * 64) << 9;

  f32x4 zero = {0.f, 0.f, 0.f, 0.f};
  f32x4 acc[8];
#pragma unroll
  for (int i = 0; i < 8; i++) acc[i] = zero;

  for (int kc = 0; kc < S_; kc += 64) {
#pragma unroll
    for (int i = 0; i < 4; i++) {
      int id = wave * 4 + i;
      int n  = id >> 1;
      int kw = id & 1;
      const short* g = VTb + (size_t)(n * 16 + l16) * S_ + kc + kw * 32 + quad * 8;
      gl_lds16(g, vbuf + id * 512);
    }
#pragma unroll
    for (int kwi = 0; kwi < 2; kwi++) {
      const short* g = Pf + tilebase + (size_t)((kc >> 5) + kwi) * 512 + lane * 8;
      gl_lds16(g, abuf + (wave * 2 + kwi) * 512);
    }
    __syncthreads();
#pragma unroll
    for (int kw = 0; kw < 2; kw++) {
      bf16x8 a = *(const bf16x8*)(abuf + (wave * 2 + kw) * 512 + lane * 8);
#pragma unroll
      for (int n = 0; n < 8; n++) {
        bf16x8 vb = *(const bf16x8*)(vbuf + (n * 2 + kw) * 512 + lane * 8);
        acc[n] = mfma16(a, vb, acc[n]);
      }
    }
    __syncthreads();
  }

  const int q0 = qt16 * 16;
#pragma unroll
  for (int n = 0; n < 8; n++) {
    int col = hs * 128 + n * 16 + l16;
#pragma unroll
    for (int r = 0; r < 4; r++) {
      int q = q0 + quad * 4 + r;
      out[((size_t)b * S_ + q) * H_ + col] = acc[n][r];
    }
  }
}

extern "C" void kernel_launch(void* const* d_in, const int* in_sizes, int n_in,
                              void* d_out, int out_size, void* d_ws, size_t ws_size,
                              hipStream_t stream) {
  const float* x  = (const float*)d_in[0];
  const float* Wq = (const float*)d_in[1];
  const float* bq = (const float*)d_in[2];
  const float* Wk = (const float*)d_in[3];
  const float* bk = (const float*)d_in[4];
  const float* Wv = (const float*)d_in[5];
  const float* bv = (const float*)d_in[6];

  short* xb  = (short*)d_ws;                       // 8 MiB
  short* wqb = xb  + (size_t)BS_ * H_;             // 128 KiB each
  short* wkb = wqb + H_ * H_;
  short* wvb = wkb + H_ * H_;
  short* Qs  = wvb + H_ * H_;                      // 8 MiB
  short* Ks  = Qs  + (size_t)BS_ * H_;             // 8 MiB
  short* VT  = Ks  + (size_t)BS_ * H_;             // 8 MiB
  short* P   = VT  + (size_t)BS_ * H_;             // 64 MiB (frag-linearized)
  float* den = (float*)(P + (size_t)B_ * S_ * S_); // 64 KiB
  float* rcp = den + BS_;                          // 64 KiB
  float* outp = (float*)d_out;

  cvt_bf16<<<1024, 256, 0, stream>>>(x, Wq, Wk, Wv, xb, wqb, wkb, wvb);
  qkv_proj<<<dim3(BS_ / 64, 3), 256, 0, stream>>>(xb, wqb, bq, wkb, bk, wvb, bv, Qs, Ks, VT);
  zero_den<<<64, 256, 0, stream>>>(den);
  scores<<<2048, 256, 0, stream>>>(Qs, Ks, P, den);
  den_rcp<<<64, 256, 0, stream>>>(den, rcp);
  vscale<<<4096, 256, 0, stream>>>(VT, rcp);
  pv<<<512, 256, 0, stream>>>(P, VT, outp);
}